// Round 8
// baseline (5595.113 us; speedup 1.0000x reference)
//
#include <hip/hip_runtime.h>
#include <cstddef>
#include <cstdint>

#define TS 256
#define NB 1024
#define NROWS 4   // rows per wave; 1 wave per block; 256 blocks = 1024 rows

// ---- LDS layout (float offsets) ----
// Bank rule (verified r7: conflicts 2.045e8 -> 3.7e4): ds_read_b128 per-lane
// stride S floats -> 16B slot = (S/4*lane)%8; need S/4 odd.
#define OW_SENSE 0        // 30x12
#define OW_ZR    360      // 60x60: z rows 0-29, r rows 30-59
#define OW_HE    3960     // 60x60: h rows 0-29, expand rows 30-59 (cols 27+ zero)
#define OW_PHI   7560     // 90x92
#define OW_IC    15840    // 27x100 (k-split halves at +0/+48)
#define OW_I3    18540    // 90x28: iS 0-29, iM 30-59, iD 60-89
#define OW_COMP  21060    // 27x36
#define OW_OC    22032    // 27x100
#define OW_OE    24732    // 30x28
#define OW_OUT   25572    // 4x36
#define OACT     25716
#define ACT_STRIDE 568    // 16B-aligned; 142 slots, 142%8=6 -> rows land on distinct banks
// per-row activation offsets
#define A_COMB 0     // sensed 0-29, M 30-59
#define A_HIN  60    // sensed 0-29, r*M 30-59
#define A_CMP  120   // compressed 0-26, zeros 27-59
#define A_AS   180   // 92: S_new, M_new, D (+2 pad)
#define A_GT   272   // 96: gated (+6 pad)
#define A_IC   368   // 32
#define A_CO   400   // 96 (+6 pad)
#define A_OC   496   // 32
#define A_DEC  528   // 32
#define A_OBS  560   // 8
#define SM_TOTAL (OACT + NROWS*ACT_STRIDE)   // 27988 floats = 111952 B -> 1 block/CU

#define FMA4(A_, W_, X_) do { \
    (A_).x = fmaf((W_).x, (X_).x, (A_).x); \
    (A_).y = fmaf((W_).y, (X_).y, (A_).y); \
    (A_).z = fmaf((W_).z, (X_).z, (A_).z); \
    (A_).w = fmaf((W_).w, (X_).w, (A_).w); } while (0)

__device__ __forceinline__ float red4(float4 a) { return (a.x + a.y) + (a.z + a.w); }
__device__ __forceinline__ float ftanh(float x) {
    float e = __expf(2.0f * x);
    return 1.0f - 2.0f / (e + 1.0f);
}
__device__ __forceinline__ float fsig(float x) {
    return 1.0f / (1.0f + __expf(-x));
}

__launch_bounds__(64)
__global__ void anima_kernel(
    const float* __restrict__ obs,
    const float* __restrict__ sense_w, const float* __restrict__ sense_b,
    const float* __restrict__ compress_w, const float* __restrict__ compress_b,
    const float* __restrict__ expand_w, const float* __restrict__ expand_b,
    const float* __restrict__ gru_z_w, const float* __restrict__ gru_z_b,
    const float* __restrict__ gru_r_w, const float* __restrict__ gru_r_b,
    const float* __restrict__ gru_h_w, const float* __restrict__ gru_h_b,
    const float* __restrict__ ic_w, const float* __restrict__ ic_b,
    const float* __restrict__ iS_w, const float* __restrict__ iS_b,
    const float* __restrict__ iM_w, const float* __restrict__ iM_b,
    const float* __restrict__ iD_w, const float* __restrict__ iD_b,
    const float* __restrict__ phi_w, const float* __restrict__ phi_b,
    const float* __restrict__ oc_w, const float* __restrict__ oc_b,
    const float* __restrict__ oe_w, const float* __restrict__ oe_b,
    const float* __restrict__ out_w, const float* __restrict__ out_b,
    float* __restrict__ out)
{
    extern __shared__ float sm[];
    const int lane = threadIdx.x;            // single 64-lane wave per block
    const int row0 = blockIdx.x * NROWS;

    // zero all LDS (pads must be 0)
    for (int i = lane; i < SM_TOTAL; i += 64) sm[i] = 0.0f;
    __syncthreads();

#define LOADW(OFF, SRC, OUTD, K, KP) \
    for (int i = lane; i < (OUTD)*(K); i += 64) { int o = i/(K); int kk = i - o*(K); sm[(OFF) + o*(KP) + kk] = SRC[i]; }
    LOADW(OW_SENSE, sense_w, 30, 8, 12)
    LOADW(OW_ZR, gru_z_w, 30, 60, 60)
    LOADW(OW_ZR + 1800, gru_r_w, 30, 60, 60)
    LOADW(OW_HE, gru_h_w, 30, 60, 60)
    LOADW(OW_HE + 1800, expand_w, 30, 27, 60)
    LOADW(OW_PHI, phi_w, 90, 90, 92)
    LOADW(OW_IC, ic_w, 27, 90, 100)
    LOADW(OW_I3, iS_w, 30, 27, 28)
    LOADW(OW_I3 + 840, iM_w, 30, 27, 28)
    LOADW(OW_I3 + 1680, iD_w, 30, 27, 28)
    LOADW(OW_COMP, compress_w, 27, 30, 36)
    LOADW(OW_OC, oc_w, 27, 90, 100)
    LOADW(OW_OE, oe_w, 30, 27, 28)
    LOADW(OW_OUT, out_w, 4, 30, 36)
#undef LOADW

    // Per-row activation bases. Only indexed inside fully-unrolled loops
    // (rule #20: unroll => compile-time index => stays in registers).
    float* Ar[NROWS];
    #pragma unroll
    for (int r = 0; r < NROWS; ++r) Ar[r] = sm + OACT + r * ACT_STRIDE;

    if (lane < 8) {
        #pragma unroll
        for (int r = 0; r < NROWS; ++r)
            Ar[r][A_OBS + lane] = obs[(size_t)(row0 + r) * 8 + lane];
    }

    // biases into registers (per-lane roles, shared by all rows)
    float b_p1  = (lane < 30) ? sense_b[lane] : 0.0f;
    float b_p2  = (lane < 30) ? gru_z_b[lane] : (lane < 60 ? gru_r_b[lane - 30] : 0.0f);
    float b_cmp = (lane < 27) ? compress_b[lane] : 0.0f;
    float b_p3  = (lane < 30) ? gru_h_b[lane] : (lane < 60 ? expand_b[lane - 30] : 0.0f);
    float b_phi0 = phi_b[lane];
    float b_phi1 = (lane < 26) ? phi_b[64 + lane] : 0.0f;
    float b_ic  = (lane < 27) ? ic_b[lane] : 0.0f;
    float b_i30 = (lane < 30) ? iS_b[lane] : (lane < 60 ? iM_b[lane - 30] : iD_b[lane - 60]);
    float b_i31 = (lane < 26) ? iD_b[4 + lane] : 0.0f;
    float b_oc  = (lane < 27) ? oc_b[lane] : 0.0f;
    float b_oe  = (lane < 30) ? oe_b[lane] : 0.0f;
    float b_out = (lane < 4) ? out_b[lane] : 0.0f;

    float Mc[NROWS], Dc[NROWS], zc[NROWS];
    #pragma unroll
    for (int r = 0; r < NROWS; ++r) { Mc[r] = 0.0f; Dc[r] = 0.0f; zc[r] = 0.0f; }

    __syncthreads();

    for (int t = 0; t < TS; ++t) {
        // ---- P1: sensed = tanh(obs @ sense_w^T + b)
        if (lane < 30) {
            const float4* w4 = (const float4*)(sm + OW_SENSE + lane * 12);
            float4 acc[NROWS];
            #pragma unroll
            for (int r = 0; r < NROWS; ++r) acc[r] = {b_p1, 0.f, 0.f, 0.f};
            #pragma unroll
            for (int i = 0; i < 2; ++i) {
                float4 w = w4[i];
                #pragma unroll
                for (int r = 0; r < NROWS; ++r) {
                    float4 x = ((const float4*)(Ar[r] + A_OBS))[i];
                    FMA4(acc[r], w, x);
                }
            }
            #pragma unroll
            for (int r = 0; r < NROWS; ++r) {
                float s = ftanh(red4(acc[r]));
                Ar[r][A_COMB + lane] = s;
                Ar[r][A_HIN + lane] = s;
            }
        }
        __syncthreads();

        // prefetch next obs (consumed at step end)
        float nxt[NROWS];
        #pragma unroll
        for (int r = 0; r < NROWS; ++r) nxt[r] = 0.0f;
        if (lane < 8 && t + 1 < TS) {
            #pragma unroll
            for (int r = 0; r < NROWS; ++r)
                nxt[r] = obs[((size_t)(t + 1) * NB + row0 + r) * 8 + lane];
        }

        // ---- P2: z (lanes 0-29), r-gate (lanes 30-59); compress (lanes 0-26)
        if (lane < 60) {
            const float4* w4 = (const float4*)(sm + OW_ZR + lane * 60);
            float4 acc[NROWS];
            #pragma unroll
            for (int r = 0; r < NROWS; ++r) acc[r] = {b_p2, 0.f, 0.f, 0.f};
            #pragma unroll
            for (int i = 0; i < 15; ++i) {
                float4 w = w4[i];
                #pragma unroll
                for (int r = 0; r < NROWS; ++r) {
                    float4 x = ((const float4*)(Ar[r] + A_COMB))[i];
                    FMA4(acc[r], w, x);
                }
            }
            #pragma unroll
            for (int r = 0; r < NROWS; ++r) {
                float g = fsig(red4(acc[r]));
                if (lane < 30) zc[r] = g;
                else           Ar[r][A_HIN + lane] = g * Ar[r][A_COMB + lane];
            }
        }
        if (lane < 27) {
            const float4* w4 = (const float4*)(sm + OW_COMP + lane * 36);
            float4 acc[NROWS];
            #pragma unroll
            for (int r = 0; r < NROWS; ++r) acc[r] = {b_cmp, 0.f, 0.f, 0.f};
            #pragma unroll
            for (int i = 0; i < 8; ++i) {
                float4 w = w4[i];
                #pragma unroll
                for (int r = 0; r < NROWS; ++r) {
                    float4 x = ((const float4*)(Ar[r] + A_COMB))[i];
                    FMA4(acc[r], w, x);
                }
            }
            #pragma unroll
            for (int r = 0; r < NROWS; ++r)
                Ar[r][A_CMP + lane] = ftanh(red4(acc[r]));
        }
        __syncthreads();

        // ---- P3: h (lanes 0-29 over HIN) / S_new=expand (lanes 30-59 over CMP)
        if (lane < 60) {
            const float4* w4 = (const float4*)(sm + OW_HE + lane * 60);
            const int xoff = (lane < 30 ? A_HIN : A_CMP);
            float4 acc[NROWS];
            #pragma unroll
            for (int r = 0; r < NROWS; ++r) acc[r] = {b_p3, 0.f, 0.f, 0.f};
            #pragma unroll
            for (int i = 0; i < 15; ++i) {
                float4 w = w4[i];
                #pragma unroll
                for (int r = 0; r < NROWS; ++r) {
                    float4 x = ((const float4*)(Ar[r] + xoff))[i];
                    FMA4(acc[r], w, x);
                }
            }
            #pragma unroll
            for (int r = 0; r < NROWS; ++r) {
                float v = ftanh(red4(acc[r]));
                if (lane < 30) {
                    float m_new = fmaf(zc[r], v - Mc[r], Mc[r]);
                    Ar[r][A_AS + 30 + lane] = m_new;
                    Ar[r][A_AS + 60 + lane] = Dc[r];
                } else {
                    Ar[r][A_AS + (lane - 30)] = v;
                }
            }
        }
        __syncthreads();

        // ---- P4: gate = sigmoid(AS @ phi^T + b); GT = AS * gate (90 outs)
        {
            const float4* w0 = (const float4*)(sm + OW_PHI + lane * 92);
            const float4* w1 = (const float4*)(sm + OW_PHI + (64 + lane) * 92);
            float4 a0[NROWS], a1[NROWS];
            #pragma unroll
            for (int r = 0; r < NROWS; ++r) {
                a0[r] = {b_phi0, 0.f, 0.f, 0.f};
                a1[r] = {b_phi1, 0.f, 0.f, 0.f};
            }
            #pragma unroll
            for (int i = 0; i < 23; ++i) {
                float4 w = w0[i];
                float4 v = w1[i];
                #pragma unroll
                for (int r = 0; r < NROWS; ++r) {
                    float4 x = ((const float4*)(Ar[r] + A_AS))[i];
                    FMA4(a0[r], w, x);
                    FMA4(a1[r], v, x);
                }
            }
            #pragma unroll
            for (int r = 0; r < NROWS; ++r) {
                float g0 = fsig(red4(a0[r]));
                Ar[r][A_GT + lane] = Ar[r][A_AS + lane] * g0;
                if (lane < 26) {
                    float g1 = fsig(red4(a1[r]));
                    Ar[r][A_GT + 64 + lane] = Ar[r][A_AS + 64 + lane] * g1;
                }
            }
        }
        __syncthreads();

        // ---- P5: inter_c = tanh(GT @ ic_w^T + b) (27 outs, k-split halves)
        {
            const int half = lane >> 5, sub = lane & 31;
            const float4* w4 = (const float4*)(sm + OW_IC + sub * 100 + half * 48);
            float4 acc[NROWS];
            #pragma unroll
            for (int r = 0; r < NROWS; ++r) acc[r] = {0.f, 0.f, 0.f, 0.f};
            #pragma unroll
            for (int i = 0; i < 12; ++i) {
                float4 w = w4[i];
                #pragma unroll
                for (int r = 0; r < NROWS; ++r) {
                    float4 x = ((const float4*)(Ar[r] + A_GT + half * 48))[i];
                    FMA4(acc[r], w, x);
                }
            }
            #pragma unroll
            for (int r = 0; r < NROWS; ++r) {
                float p = red4(acc[r]);
                p += __shfl_xor(p, 32);
                if (lane < 27) Ar[r][A_IC + lane] = ftanh(p + b_ic);
            }
        }
        __syncthreads();

        // ---- P6: S_int/M_int/D_new -> CO (90 outs)
        {
            const float4* w0 = (const float4*)(sm + OW_I3 + lane * 28);
            const float4* w1 = (const float4*)(sm + OW_I3 + (64 + lane) * 28);
            float4 a0[NROWS], a1[NROWS];
            #pragma unroll
            for (int r = 0; r < NROWS; ++r) {
                a0[r] = {b_i30, 0.f, 0.f, 0.f};
                a1[r] = {b_i31, 0.f, 0.f, 0.f};
            }
            #pragma unroll
            for (int i = 0; i < 7; ++i) {
                float4 w = w0[i];
                float4 v = w1[i];
                #pragma unroll
                for (int r = 0; r < NROWS; ++r) {
                    float4 x = ((const float4*)(Ar[r] + A_IC))[i];
                    FMA4(a0[r], w, x);
                    FMA4(a1[r], v, x);
                }
            }
            #pragma unroll
            for (int r = 0; r < NROWS; ++r) {
                Ar[r][A_CO + lane] = ftanh(red4(a0[r]));
                if (lane < 26) Ar[r][A_CO + 64 + lane] = ftanh(red4(a1[r]));
            }
        }
        __syncthreads();

        // ---- P7: out_c = tanh(CO @ oc_w^T + b) (k-split); carry update
        {
            const int half = lane >> 5, sub = lane & 31;
            const float4* w4 = (const float4*)(sm + OW_OC + sub * 100 + half * 48);
            float4 acc[NROWS];
            #pragma unroll
            for (int r = 0; r < NROWS; ++r) acc[r] = {0.f, 0.f, 0.f, 0.f};
            #pragma unroll
            for (int i = 0; i < 12; ++i) {
                float4 w = w4[i];
                #pragma unroll
                for (int r = 0; r < NROWS; ++r) {
                    float4 x = ((const float4*)(Ar[r] + A_CO + half * 48))[i];
                    FMA4(acc[r], w, x);
                }
            }
            #pragma unroll
            for (int r = 0; r < NROWS; ++r) {
                float p = red4(acc[r]);
                p += __shfl_xor(p, 32);
                if (lane < 27) Ar[r][A_OC + lane] = ftanh(p + b_oc);
            }
            if (lane < 30) {
                #pragma unroll
                for (int r = 0; r < NROWS; ++r) {
                    Mc[r] = Ar[r][A_CO + 30 + lane];
                    Dc[r] = Ar[r][A_CO + 60 + lane];
                    Ar[r][A_COMB + 30 + lane] = Mc[r];   // publish M for next P2
                }
            }
        }
        __syncthreads();

        // ---- P8: decision = tanh(OC @ oe_w^T + b)
        if (lane < 30) {
            const float4* w4 = (const float4*)(sm + OW_OE + lane * 28);
            float4 acc[NROWS];
            #pragma unroll
            for (int r = 0; r < NROWS; ++r) acc[r] = {b_oe, 0.f, 0.f, 0.f};
            #pragma unroll
            for (int i = 0; i < 7; ++i) {
                float4 w = w4[i];
                #pragma unroll
                for (int r = 0; r < NROWS; ++r) {
                    float4 x = ((const float4*)(Ar[r] + A_OC))[i];
                    FMA4(acc[r], w, x);
                }
            }
            #pragma unroll
            for (int r = 0; r < NROWS; ++r)
                Ar[r][A_DEC + lane] = ftanh(red4(acc[r]));
        }
        __syncthreads();

        // ---- P9: action -> global; write next obs
        if (lane < 4) {
            const float4* w4 = (const float4*)(sm + OW_OUT + lane * 36);
            float4 acc[NROWS];
            #pragma unroll
            for (int r = 0; r < NROWS; ++r) acc[r] = {b_out, 0.f, 0.f, 0.f};
            #pragma unroll
            for (int i = 0; i < 8; ++i) {
                float4 w = w4[i];
                #pragma unroll
                for (int r = 0; r < NROWS; ++r) {
                    float4 x = ((const float4*)(Ar[r] + A_DEC))[i];
                    FMA4(acc[r], w, x);
                }
            }
            #pragma unroll
            for (int r = 0; r < NROWS; ++r)
                out[((size_t)t * NB + row0 + r) * 4 + lane] = red4(acc[r]);
        }
        if (lane < 8 && t + 1 < TS) {
            #pragma unroll
            for (int r = 0; r < NROWS; ++r)
                Ar[r][A_OBS + lane] = nxt[r];
        }
        __syncthreads();
    }
}

extern "C" void kernel_launch(void* const* d_in, const int* in_sizes, int n_in,
                              void* d_out, int out_size, void* d_ws, size_t ws_size,
                              hipStream_t stream) {
    const float* obs        = (const float*)d_in[0];
    const float* sense_w    = (const float*)d_in[1];
    const float* sense_b    = (const float*)d_in[2];
    const float* compress_w = (const float*)d_in[3];
    const float* compress_b = (const float*)d_in[4];
    const float* expand_w   = (const float*)d_in[5];
    const float* expand_b   = (const float*)d_in[6];
    const float* gru_z_w    = (const float*)d_in[7];
    const float* gru_z_b    = (const float*)d_in[8];
    const float* gru_r_w    = (const float*)d_in[9];
    const float* gru_r_b    = (const float*)d_in[10];
    const float* gru_h_w    = (const float*)d_in[11];
    const float* gru_h_b    = (const float*)d_in[12];
    const float* ic_w       = (const float*)d_in[13];
    const float* ic_b       = (const float*)d_in[14];
    const float* iS_w       = (const float*)d_in[15];
    const float* iS_b       = (const float*)d_in[16];
    const float* iM_w       = (const float*)d_in[17];
    const float* iM_b       = (const float*)d_in[18];
    const float* iD_w       = (const float*)d_in[19];
    const float* iD_b       = (const float*)d_in[20];
    const float* phi_w      = (const float*)d_in[21];
    const float* phi_b      = (const float*)d_in[22];
    const float* oc_w       = (const float*)d_in[23];
    const float* oc_b       = (const float*)d_in[24];
    const float* oe_w       = (const float*)d_in[25];
    const float* oe_b       = (const float*)d_in[26];
    const float* out_w      = (const float*)d_in[27];
    const float* out_b      = (const float*)d_in[28];
    float* out = (float*)d_out;

    size_t shmem = (size_t)SM_TOTAL * sizeof(float);
    (void)hipFuncSetAttribute((const void*)anima_kernel,
                              hipFuncAttributeMaxDynamicSharedMemorySize, (int)shmem);
    anima_kernel<<<dim3(NB / NROWS), dim3(64), shmem, stream>>>(
        obs, sense_w, sense_b, compress_w, compress_b, expand_w, expand_b,
        gru_z_w, gru_z_b, gru_r_w, gru_r_b, gru_h_w, gru_h_b,
        ic_w, ic_b, iS_w, iS_b, iM_w, iM_b, iD_w, iD_b,
        phi_w, phi_b, oc_w, oc_b, oe_w, oe_b, out_w, out_b, out);
}

// Round 9
// 1181.496 us; speedup vs baseline: 4.7356x; 4.7356x over previous
//
#include <hip/hip_runtime.h>
#include <cstddef>
#include <cstdint>

#define TS 256
#define NB 1024

// ---- LDS layout (float offsets) ----
// Bank rule (verified r7: conflicts 2.045e8 -> 3.7e4): ds_read_b128 per-lane
// float-stride S -> 16B slot = (S/4*lane)%8; need S/4 odd.
// 60->15 ok, 92->23 ok, 28->7 ok; padded: IC/OC=100(25), COMP/OUT=36(9), SENSE=12(3).
#define OW_SENSE 0        // 30x12
#define OW_ZR    360      // 60x60: z rows 0-29, r rows 30-59
#define OW_HE    3960     // 60x60: h rows 0-29, expand rows 30-59 (cols 27+ zero)
#define OW_PHI   7560     // 90x92
#define OW_IC    15840    // 27x100 (k-split halves at +0/+48)
#define OW_I3    18540    // 90x28: iS 0-29, iM 30-59, iD 60-89
#define OW_COMP  21060    // 27x36
#define OW_OC    22032    // 27x100
#define OW_OE    24732    // 30x28
#define OW_OUT   25572    // 4x36
#define OACT     25716
#define ACT_STRIDE 568    // 16B-aligned
// per-row activation offsets (one segment per wave == per row)
#define A_COMB 0     // sensed 0-29, M 30-59
#define A_HIN  60    // sensed 0-29, r*M 30-59
#define A_CMP  120   // compressed 0-26, zeros 27-59
#define A_AS   180   // 92: S_new, M_new, D (+2 pad)
#define A_GT   272   // 96: gated (+6 pad)
#define A_IC   368   // 32
#define A_CO   400   // 96 (+6 pad)
#define A_OC   496   // 32
#define A_DEC  528   // 32
#define A_OBS  560   // 8
#define SM_TOTAL (OACT + 4*ACT_STRIDE)   // 27988 floats = 111952 B -> 1 block/CU

#define FMA4(A_, W_, X_) do { \
    (A_).x = fmaf((W_).x, (X_).x, (A_).x); \
    (A_).y = fmaf((W_).y, (X_).y, (A_).y); \
    (A_).z = fmaf((W_).z, (X_).z, (A_).z); \
    (A_).w = fmaf((W_).w, (X_).w, (A_).w); } while (0)

__device__ __forceinline__ float red4(float4 a) { return (a.x + a.y) + (a.z + a.w); }
__device__ __forceinline__ float ftanh(float x) {
    float e = __expf(2.0f * x);
    return 1.0f - 2.0f / (e + 1.0f);
}
__device__ __forceinline__ float fsig(float x) {
    return 1.0f / (1.0f + __expf(-x));
}

// NO in-loop __syncthreads: each wave owns one row end-to-end (its own
// activation segment; weights read-only after the single init barrier;
// __shfl_xor is intra-wave). Intra-wave LDS RAW ordering is enforced by
// compiler-inserted lgkmcnt waits. Barriers only forced 4-wave lockstep
// (drain + port bursts) — removing them is the r9 lever.
__launch_bounds__(256)
__global__ void anima_kernel(
    const float* __restrict__ obs,
    const float* __restrict__ sense_w, const float* __restrict__ sense_b,
    const float* __restrict__ compress_w, const float* __restrict__ compress_b,
    const float* __restrict__ expand_w, const float* __restrict__ expand_b,
    const float* __restrict__ gru_z_w, const float* __restrict__ gru_z_b,
    const float* __restrict__ gru_r_w, const float* __restrict__ gru_r_b,
    const float* __restrict__ gru_h_w, const float* __restrict__ gru_h_b,
    const float* __restrict__ ic_w, const float* __restrict__ ic_b,
    const float* __restrict__ iS_w, const float* __restrict__ iS_b,
    const float* __restrict__ iM_w, const float* __restrict__ iM_b,
    const float* __restrict__ iD_w, const float* __restrict__ iD_b,
    const float* __restrict__ phi_w, const float* __restrict__ phi_b,
    const float* __restrict__ oc_w, const float* __restrict__ oc_b,
    const float* __restrict__ oe_w, const float* __restrict__ oe_b,
    const float* __restrict__ out_w, const float* __restrict__ out_b,
    float* __restrict__ out)
{
    extern __shared__ float sm[];
    const int tid = threadIdx.x;
    const int wid = tid >> 6;
    const int lane = tid & 63;
    const int row = blockIdx.x * 4 + wid;

    // zero all LDS (pads must be 0)
    for (int i = tid; i < SM_TOTAL; i += 256) sm[i] = 0.0f;
    __syncthreads();

#define LOADW(OFF, SRC, OUTD, K, KP) \
    for (int i = tid; i < (OUTD)*(K); i += 256) { int o = i/(K); int kk = i - o*(K); sm[(OFF) + o*(KP) + kk] = SRC[i]; }
    LOADW(OW_SENSE, sense_w, 30, 8, 12)
    LOADW(OW_ZR, gru_z_w, 30, 60, 60)
    LOADW(OW_ZR + 1800, gru_r_w, 30, 60, 60)
    LOADW(OW_HE, gru_h_w, 30, 60, 60)
    LOADW(OW_HE + 1800, expand_w, 30, 27, 60)
    LOADW(OW_PHI, phi_w, 90, 90, 92)
    LOADW(OW_IC, ic_w, 27, 90, 100)
    LOADW(OW_I3, iS_w, 30, 27, 28)
    LOADW(OW_I3 + 840, iM_w, 30, 27, 28)
    LOADW(OW_I3 + 1680, iD_w, 30, 27, 28)
    LOADW(OW_COMP, compress_w, 27, 30, 36)
    LOADW(OW_OC, oc_w, 27, 90, 100)
    LOADW(OW_OE, oe_w, 30, 27, 28)
    LOADW(OW_OUT, out_w, 4, 30, 36)
#undef LOADW

    float* A = sm + OACT + wid * ACT_STRIDE;
    if (lane < 8) A[A_OBS + lane] = obs[(size_t)row * 8 + lane];

    // biases into registers (per-lane roles)
    float b_p1  = (lane < 30) ? sense_b[lane] : 0.0f;
    float b_p2  = (lane < 30) ? gru_z_b[lane] : (lane < 60 ? gru_r_b[lane - 30] : 0.0f);
    float b_cmp = (lane < 27) ? compress_b[lane] : 0.0f;
    float b_p3  = (lane < 30) ? gru_h_b[lane] : (lane < 60 ? expand_b[lane - 30] : 0.0f);
    float b_phi0 = phi_b[lane];
    float b_phi1 = (lane < 26) ? phi_b[64 + lane] : 0.0f;
    float b_ic  = (lane < 27) ? ic_b[lane] : 0.0f;
    float b_i30 = (lane < 30) ? iS_b[lane] : (lane < 60 ? iM_b[lane - 30] : iD_b[lane - 60]);
    float b_i31 = (lane < 26) ? iD_b[4 + lane] : 0.0f;
    float b_oc  = (lane < 27) ? oc_b[lane] : 0.0f;
    float b_oe  = (lane < 30) ? oe_b[lane] : 0.0f;
    float b_out = (lane < 4) ? out_b[lane] : 0.0f;

    float M_reg = 0.0f, D_reg = 0.0f, z_reg = 0.0f;

    __syncthreads();   // the ONLY barrier: weights/zeros visible to all waves

    for (int t = 0; t < TS; ++t) {
        // ---- P1: sensed = tanh(obs @ sense_w^T + b) -> COMB[0:30], HIN[0:30]
        if (lane < 30) {
            const float4* w4 = (const float4*)(sm + OW_SENSE + lane * 12);
            const float4* x4 = (const float4*)(A + A_OBS);
            float4 a = {b_p1, 0.f, 0.f, 0.f};
            float4 w, x;
            w = w4[0]; x = x4[0]; FMA4(a, w, x);
            w = w4[1]; x = x4[1]; FMA4(a, w, x);
            float s = ftanh(red4(a));
            A[A_COMB + lane] = s;
            A[A_HIN + lane] = s;
        }

        // prefetch next obs (consumed at step end; latency hidden under compute)
        float nxt = 0.0f;
        if (lane < 8 && t + 1 < TS) nxt = obs[((size_t)(t + 1) * NB + row) * 8 + lane];

        // ---- P2: z (lanes 0-29), r-gate (lanes 30-59); compress (lanes 0-26)
        if (lane < 60) {
            const float4* w4 = (const float4*)(sm + OW_ZR + lane * 60);
            const float4* x4 = (const float4*)(A + A_COMB);
            float4 a = {b_p2, 0.f, 0.f, 0.f};
            #pragma unroll
            for (int i = 0; i < 15; ++i) { float4 w = w4[i], x = x4[i]; FMA4(a, w, x); }
            float g = fsig(red4(a));
            if (lane < 30) z_reg = g;
            else           A[A_HIN + lane] = g * A[A_COMB + lane];
        }
        if (lane < 27) {
            const float4* w4 = (const float4*)(sm + OW_COMP + lane * 36);
            const float4* x4 = (const float4*)(A + A_COMB);
            float4 a = {b_cmp, 0.f, 0.f, 0.f};
            #pragma unroll
            for (int i = 0; i < 8; ++i) { float4 w = w4[i], x = x4[i]; FMA4(a, w, x); }
            A[A_CMP + lane] = ftanh(red4(a));
        }

        // ---- P3: h (lanes 0-29 over HIN) / S_new=expand (lanes 30-59 over CMP)
        if (lane < 60) {
            const float4* w4 = (const float4*)(sm + OW_HE + lane * 60);
            const float4* x4 = (const float4*)(A + (lane < 30 ? A_HIN : A_CMP));
            float4 a = {b_p3, 0.f, 0.f, 0.f};
            #pragma unroll
            for (int i = 0; i < 15; ++i) { float4 w = w4[i], x = x4[i]; FMA4(a, w, x); }
            float v = ftanh(red4(a));
            if (lane < 30) {
                float m_new = fmaf(z_reg, v - M_reg, M_reg);
                A[A_AS + 30 + lane] = m_new;
                A[A_AS + 60 + lane] = D_reg;
            } else {
                A[A_AS + (lane - 30)] = v;
            }
        }

        // ---- P4: gate = sigmoid(AS @ phi^T + b); GT = AS * gate (90 outs)
        {
            const float4* x4 = (const float4*)(A + A_AS);
            const float4* w0 = (const float4*)(sm + OW_PHI + lane * 92);
            const float4* w1 = (const float4*)(sm + OW_PHI + (64 + lane) * 92); // junk for lane>=26, discarded
            float4 a0 = {b_phi0, 0.f, 0.f, 0.f};
            float4 a1 = {b_phi1, 0.f, 0.f, 0.f};
            #pragma unroll
            for (int i = 0; i < 23; ++i) {
                float4 x = x4[i];
                float4 w = w0[i]; FMA4(a0, w, x);
                float4 v = w1[i]; FMA4(a1, v, x);
            }
            float g0 = fsig(red4(a0));
            A[A_GT + lane] = A[A_AS + lane] * g0;
            if (lane < 26) {
                float g1 = fsig(red4(a1));
                A[A_GT + 64 + lane] = A[A_AS + 64 + lane] * g1;
            }
        }

        // ---- P5: inter_c = tanh(GT @ ic_w^T + b) (27 outs, k-split halves)
        {
            const int half = lane >> 5, sub = lane & 31;
            const float4* x4 = (const float4*)(A + A_GT + half * 48);
            const float4* w4 = (const float4*)(sm + OW_IC + sub * 100 + half * 48);
            float4 a = {0.f, 0.f, 0.f, 0.f};
            #pragma unroll
            for (int i = 0; i < 12; ++i) { float4 x = x4[i], w = w4[i]; FMA4(a, w, x); }
            float part = red4(a);
            part += __shfl_xor(part, 32);
            if (lane < 27) A[A_IC + lane] = ftanh(part + b_ic);
        }

        // ---- P6: S_int/M_int/D_new -> CO (90 outs)
        {
            const float4* x4 = (const float4*)(A + A_IC);
            const float4* w0 = (const float4*)(sm + OW_I3 + lane * 28);
            const float4* w1 = (const float4*)(sm + OW_I3 + (64 + lane) * 28);
            float4 a0 = {b_i30, 0.f, 0.f, 0.f};
            float4 a1 = {b_i31, 0.f, 0.f, 0.f};
            #pragma unroll
            for (int i = 0; i < 7; ++i) {
                float4 x = x4[i];
                float4 w = w0[i]; FMA4(a0, w, x);
                float4 v = w1[i]; FMA4(a1, v, x);
            }
            A[A_CO + lane] = ftanh(red4(a0));
            if (lane < 26) A[A_CO + 64 + lane] = ftanh(red4(a1));
        }

        // ---- P7: out_c = tanh(CO @ oc_w^T + b) (k-split); carry update
        {
            const int half = lane >> 5, sub = lane & 31;
            const float4* x4 = (const float4*)(A + A_CO + half * 48);
            const float4* w4 = (const float4*)(sm + OW_OC + sub * 100 + half * 48);
            float4 a = {0.f, 0.f, 0.f, 0.f};
            #pragma unroll
            for (int i = 0; i < 12; ++i) { float4 x = x4[i], w = w4[i]; FMA4(a, w, x); }
            float part = red4(a);
            part += __shfl_xor(part, 32);
            if (lane < 27) A[A_OC + lane] = ftanh(part + b_oc);
            if (lane < 30) {
                M_reg = A[A_CO + 30 + lane];
                D_reg = A[A_CO + 60 + lane];
                A[A_COMB + 30 + lane] = M_reg;   // publish M for next step's P2
            }
        }

        // ---- P8: decision = tanh(OC @ oe_w^T + b)
        if (lane < 30) {
            const float4* x4 = (const float4*)(A + A_OC);
            const float4* w4 = (const float4*)(sm + OW_OE + lane * 28);
            float4 a = {b_oe, 0.f, 0.f, 0.f};
            #pragma unroll
            for (int i = 0; i < 7; ++i) { float4 x = x4[i], w = w4[i]; FMA4(a, w, x); }
            A[A_DEC + lane] = ftanh(red4(a));
        }

        // ---- P9: action -> global; write next obs
        if (lane < 4) {
            const float4* x4 = (const float4*)(A + A_DEC);
            const float4* w4 = (const float4*)(sm + OW_OUT + lane * 36);
            float4 a = {b_out, 0.f, 0.f, 0.f};
            #pragma unroll
            for (int i = 0; i < 8; ++i) { float4 x = x4[i], w = w4[i]; FMA4(a, w, x); }
            out[((size_t)t * NB + row) * 4 + lane] = red4(a);
        }
        if (lane < 8 && t + 1 < TS) A[A_OBS + lane] = nxt;
    }
}

extern "C" void kernel_launch(void* const* d_in, const int* in_sizes, int n_in,
                              void* d_out, int out_size, void* d_ws, size_t ws_size,
                              hipStream_t stream) {
    const float* obs        = (const float*)d_in[0];
    const float* sense_w    = (const float*)d_in[1];
    const float* sense_b    = (const float*)d_in[2];
    const float* compress_w = (const float*)d_in[3];
    const float* compress_b = (const float*)d_in[4];
    const float* expand_w   = (const float*)d_in[5];
    const float* expand_b   = (const float*)d_in[6];
    const float* gru_z_w    = (const float*)d_in[7];
    const float* gru_z_b    = (const float*)d_in[8];
    const float* gru_r_w    = (const float*)d_in[9];
    const float* gru_r_b    = (const float*)d_in[10];
    const float* gru_h_w    = (const float*)d_in[11];
    const float* gru_h_b    = (const float*)d_in[12];
    const float* ic_w       = (const float*)d_in[13];
    const float* ic_b       = (const float*)d_in[14];
    const float* iS_w       = (const float*)d_in[15];
    const float* iS_b       = (const float*)d_in[16];
    const float* iM_w       = (const float*)d_in[17];
    const float* iM_b       = (const float*)d_in[18];
    const float* iD_w       = (const float*)d_in[19];
    const float* iD_b       = (const float*)d_in[20];
    const float* phi_w      = (const float*)d_in[21];
    const float* phi_b      = (const float*)d_in[22];
    const float* oc_w       = (const float*)d_in[23];
    const float* oc_b       = (const float*)d_in[24];
    const float* oe_w       = (const float*)d_in[25];
    const float* oe_b       = (const float*)d_in[26];
    const float* out_w      = (const float*)d_in[27];
    const float* out_b      = (const float*)d_in[28];
    float* out = (float*)d_out;

    size_t shmem = (size_t)SM_TOTAL * sizeof(float);
    (void)hipFuncSetAttribute((const void*)anima_kernel,
                              hipFuncAttributeMaxDynamicSharedMemorySize, (int)shmem);
    anima_kernel<<<dim3(256), dim3(256), shmem, stream>>>(
        obs, sense_w, sense_b, compress_w, compress_b, expand_w, expand_b,
        gru_z_w, gru_z_b, gru_r_w, gru_r_b, gru_h_w, gru_h_b,
        ic_w, ic_b, iS_w, iS_b, iM_w, iM_b, iD_w, iD_b,
        phi_w, phi_b, oc_w, oc_b, oe_w, oe_b, out_w, out_b, out);
}

// Round 16
// 1157.158 us; speedup vs baseline: 4.8352x; 1.0210x over previous
//
#include <hip/hip_runtime.h>
#include <cstddef>
#include <cstdint>

#define TS 256
#define NB 1024

// ---- LDS layout (float offsets) ----
// Bank rule (verified r7): ds_read_b128 per-lane float-stride S -> 16B slot =
// (S/4*lane)%8; need S/4 odd. 60->15, 92->23, 28->7 ok; padded IC/OC=100,
// COMP/OUT=36, SENSE=12.
#define OW_SENSE 0        // 30x12
#define OW_ZR    360      // 60x60: z rows 0-29, r rows 30-59
#define OW_HE    3960     // 60x60: h rows 0-29, expand rows 30-59 (cols 27+ zero)
#define OW_PHI   7560     // 90x92
#define OW_IC    15840    // 27x100 (k-split halves at +0/+48)
#define OW_I3    18540    // 90x28: iS 0-29, iM 30-59, iD 60-89
#define OW_COMP  21060    // 27x36
#define OW_OC    22032    // 27x100
#define OW_OE    24732    // 30x28
#define OW_OUT   25572    // 4x36
#define OACT     25716
#define ACT_STRIDE 568
// per-row activation offsets (one segment per wave == per row)
#define A_COMB 0     // sensed 0-29, M 30-59
#define A_HIN  60    // sensed 0-29, r*M 30-59
#define A_CMP  120   // compressed 0-26, zeros 27-59
#define A_AS   180   // 92: S_new, M_new, D (+2 pad)
#define A_GT   272   // 96: gated (+6 pad)
#define A_IC   368   // 32
#define A_CO   400   // 96 (+6 pad)
#define A_OC   496   // 32
#define A_DEC  528   // 32
#define A_OBS  560   // 8
#define SM_TOTAL (OACT + 4*ACT_STRIDE)   // 27988 floats = 111952 B -> 1 block/CU

#define FMA4(A_, W_, X_) do { \
    (A_).x = fmaf((W_).x, (X_).x, (A_).x); \
    (A_).y = fmaf((W_).y, (X_).y, (A_).y); \
    (A_).z = fmaf((W_).z, (X_).z, (A_).z); \
    (A_).w = fmaf((W_).w, (X_).w, (A_).w); } while (0)

__device__ __forceinline__ float red4(float4 a) { return (a.x + a.y) + (a.z + a.w); }
__device__ __forceinline__ float ftanh(float x) {
    float e = __expf(2.0f * x);
    return 1.0f - 2.0f / (e + 1.0f);
}
__device__ __forceinline__ float fsig(float x) {
    return 1.0f / (1.0f + __expf(-x));
}

// r9 lever kept: NO in-loop __syncthreads (each wave owns one row end-to-end).
// r10 lever: weight rows for P2/P3/P4 are t-invariant per lane -> persistent
// VGPRs (304), loaded once. __launch_bounds__(256,1) unlocks >256 VGPRs
// (1 wave/SIMD anyway; no spill through ~450 per m08).
__launch_bounds__(256, 1)
__global__ void anima_kernel(
    const float* __restrict__ obs,
    const float* __restrict__ sense_w, const float* __restrict__ sense_b,
    const float* __restrict__ compress_w, const float* __restrict__ compress_b,
    const float* __restrict__ expand_w, const float* __restrict__ expand_b,
    const float* __restrict__ gru_z_w, const float* __restrict__ gru_z_b,
    const float* __restrict__ gru_r_w, const float* __restrict__ gru_r_b,
    const float* __restrict__ gru_h_w, const float* __restrict__ gru_h_b,
    const float* __restrict__ ic_w, const float* __restrict__ ic_b,
    const float* __restrict__ iS_w, const float* __restrict__ iS_b,
    const float* __restrict__ iM_w, const float* __restrict__ iM_b,
    const float* __restrict__ iD_w, const float* __restrict__ iD_b,
    const float* __restrict__ phi_w, const float* __restrict__ phi_b,
    const float* __restrict__ oc_w, const float* __restrict__ oc_b,
    const float* __restrict__ oe_w, const float* __restrict__ oe_b,
    const float* __restrict__ out_w, const float* __restrict__ out_b,
    float* __restrict__ out)
{
    extern __shared__ float sm[];
    const int tid = threadIdx.x;
    const int wid = tid >> 6;
    const int lane = tid & 63;
    const int row = blockIdx.x * 4 + wid;

    // zero all LDS (pads must be 0)
    for (int i = tid; i < SM_TOTAL; i += 256) sm[i] = 0.0f;
    __syncthreads();

#define LOADW(OFF, SRC, OUTD, K, KP) \
    for (int i = tid; i < (OUTD)*(K); i += 256) { int o = i/(K); int kk = i - o*(K); sm[(OFF) + o*(KP) + kk] = SRC[i]; }
    LOADW(OW_SENSE, sense_w, 30, 8, 12)
    LOADW(OW_ZR, gru_z_w, 30, 60, 60)
    LOADW(OW_ZR + 1800, gru_r_w, 30, 60, 60)
    LOADW(OW_HE, gru_h_w, 30, 60, 60)
    LOADW(OW_HE + 1800, expand_w, 30, 27, 60)
    LOADW(OW_PHI, phi_w, 90, 90, 92)
    LOADW(OW_IC, ic_w, 27, 90, 100)
    LOADW(OW_I3, iS_w, 30, 27, 28)
    LOADW(OW_I3 + 840, iM_w, 30, 27, 28)
    LOADW(OW_I3 + 1680, iD_w, 30, 27, 28)
    LOADW(OW_COMP, compress_w, 27, 30, 36)
    LOADW(OW_OC, oc_w, 27, 90, 100)
    LOADW(OW_OE, oe_w, 30, 27, 28)
    LOADW(OW_OUT, out_w, 4, 30, 36)
#undef LOADW

    float* A = sm + OACT + wid * ACT_STRIDE;
    if (lane < 8) A[A_OBS + lane] = obs[(size_t)row * 8 + lane];

    // biases into registers (per-lane roles)
    float b_p1  = (lane < 30) ? sense_b[lane] : 0.0f;
    float b_p2  = (lane < 30) ? gru_z_b[lane] : (lane < 60 ? gru_r_b[lane - 30] : 0.0f);
    float b_cmp = (lane < 27) ? compress_b[lane] : 0.0f;
    float b_p3  = (lane < 30) ? gru_h_b[lane] : (lane < 60 ? expand_b[lane - 30] : 0.0f);
    float b_phi0 = phi_b[lane];
    float b_phi1 = (lane < 26) ? phi_b[64 + lane] : 0.0f;
    float b_ic  = (lane < 27) ? ic_b[lane] : 0.0f;
    float b_i30 = (lane < 30) ? iS_b[lane] : (lane < 60 ? iM_b[lane - 30] : iD_b[lane - 60]);
    float b_i31 = (lane < 26) ? iD_b[4 + lane] : 0.0f;
    float b_oc  = (lane < 27) ? oc_b[lane] : 0.0f;
    float b_oe  = (lane < 30) ? oe_b[lane] : 0.0f;
    float b_out = (lane < 4) ? out_b[lane] : 0.0f;

    float M_reg = 0.0f, D_reg = 0.0f, z_reg = 0.0f;

    __syncthreads();   // weights/zeros visible to all waves

    // ---- persistent per-lane weight rows (t-invariant) -> VGPRs ----
    // All indices compile-time (full unroll) => register arrays (rule #20).
    float4 wz[15], wh[15], wp0[23], wp1[23];
    {
        const float4* z4 = (const float4*)(sm + OW_ZR + lane * 60);
        const float4* h4 = (const float4*)(sm + OW_HE + lane * 60);
        const float4* p0 = (const float4*)(sm + OW_PHI + lane * 92);
        const float4* p1 = (const float4*)(sm + OW_PHI + (64 + lane) * 92); // lanes>=26: in-bounds junk, unused
        #pragma unroll
        for (int i = 0; i < 15; ++i) wz[i] = z4[i];
        #pragma unroll
        for (int i = 0; i < 15; ++i) wh[i] = h4[i];
        #pragma unroll
        for (int i = 0; i < 23; ++i) wp0[i] = p0[i];
        #pragma unroll
        for (int i = 0; i < 23; ++i) wp1[i] = p1[i];
    }

    for (int t = 0; t < TS; ++t) {
        // ---- P1: sensed = tanh(obs @ sense_w^T + b) -> COMB[0:30], HIN[0:30]
        if (lane < 30) {
            const float4* w4 = (const float4*)(sm + OW_SENSE + lane * 12);
            const float4* x4 = (const float4*)(A + A_OBS);
            float4 a = {b_p1, 0.f, 0.f, 0.f};
            float4 w, x;
            w = w4[0]; x = x4[0]; FMA4(a, w, x);
            w = w4[1]; x = x4[1]; FMA4(a, w, x);
            float s = ftanh(red4(a));
            A[A_COMB + lane] = s;
            A[A_HIN + lane] = s;
        }

        // prefetch next obs (latency hidden under compute)
        float nxt = 0.0f;
        if (lane < 8 && t + 1 < TS) nxt = obs[((size_t)(t + 1) * NB + row) * 8 + lane];

        // ---- P2: z (lanes 0-29), r-gate (lanes 30-59), compress folded in
        // (lanes 0-26 reuse the x registers for the first 8 iterations)
        if (lane < 60) {
            const float4* x4 = (const float4*)(A + A_COMB);
            const float4* wc4 = (const float4*)(sm + OW_COMP + lane * 36); // lanes<27
            float4 a  = {b_p2, 0.f, 0.f, 0.f};
            float4 ac = {b_cmp, 0.f, 0.f, 0.f};
            #pragma unroll
            for (int i = 0; i < 15; ++i) {
                float4 x = x4[i];
                FMA4(a, wz[i], x);
                if (i < 8 && lane < 27) { float4 wc = wc4[i]; FMA4(ac, wc, x); }
            }
            float g = fsig(red4(a));
            if (lane < 30) z_reg = g;
            else           A[A_HIN + lane] = g * A[A_COMB + lane];
            if (lane < 27) A[A_CMP + lane] = ftanh(red4(ac));
        }

        // ---- P3: h (lanes 0-29 over HIN) / S_new=expand (lanes 30-59 over CMP)
        if (lane < 60) {
            const float4* x4 = (const float4*)(A + (lane < 30 ? A_HIN : A_CMP));
            float4 a = {b_p3, 0.f, 0.f, 0.f};
            #pragma unroll
            for (int i = 0; i < 15; ++i) { float4 x = x4[i]; FMA4(a, wh[i], x); }
            float v = ftanh(red4(a));
            if (lane < 30) {
                float m_new = fmaf(z_reg, v - M_reg, M_reg);
                A[A_AS + 30 + lane] = m_new;
                A[A_AS + 60 + lane] = D_reg;
            } else {
                A[A_AS + (lane - 30)] = v;
            }
        }

        // ---- P4: gate = sigmoid(AS @ phi^T + b); GT = AS * gate (90 outs)
        {
            const float4* x4 = (const float4*)(A + A_AS);
            float4 a0 = {b_phi0, 0.f, 0.f, 0.f};
            float4 a1 = {b_phi1, 0.f, 0.f, 0.f};
            #pragma unroll
            for (int i = 0; i < 23; ++i) {
                float4 x = x4[i];
                FMA4(a0, wp0[i], x);
                FMA4(a1, wp1[i], x);
            }
            float g0 = fsig(red4(a0));
            A[A_GT + lane] = A[A_AS + lane] * g0;
            if (lane < 26) {
                float g1 = fsig(red4(a1));
                A[A_GT + 64 + lane] = A[A_AS + 64 + lane] * g1;
            }
        }

        // ---- P5: inter_c = tanh(GT @ ic_w^T + b) (27 outs, k-split halves)
        {
            const int half = lane >> 5, sub = lane & 31;
            const float4* x4 = (const float4*)(A + A_GT + half * 48);
            const float4* w4 = (const float4*)(sm + OW_IC + sub * 100 + half * 48);
            float4 a = {0.f, 0.f, 0.f, 0.f};
            #pragma unroll
            for (int i = 0; i < 12; ++i) { float4 x = x4[i], w = w4[i]; FMA4(a, w, x); }
            float part = red4(a);
            part += __shfl_xor(part, 32);
            if (lane < 27) A[A_IC + lane] = ftanh(part + b_ic);
        }

        // ---- P6: S_int/M_int/D_new -> CO (90 outs)
        {
            const float4* x4 = (const float4*)(A + A_IC);
            const float4* w0 = (const float4*)(sm + OW_I3 + lane * 28);
            const float4* w1 = (const float4*)(sm + OW_I3 + (64 + lane) * 28);
            float4 a0 = {b_i30, 0.f, 0.f, 0.f};
            float4 a1 = {b_i31, 0.f, 0.f, 0.f};
            #pragma unroll
            for (int i = 0; i < 7; ++i) {
                float4 x = x4[i];
                float4 w = w0[i]; FMA4(a0, w, x);
                float4 v = w1[i]; FMA4(a1, v, x);
            }
            A[A_CO + lane] = ftanh(red4(a0));
            if (lane < 26) A[A_CO + 64 + lane] = ftanh(red4(a1));
        }

        // ---- P7: out_c = tanh(CO @ oc_w^T + b) (k-split); carry update
        {
            const int half = lane >> 5, sub = lane & 31;
            const float4* x4 = (const float4*)(A + A_CO + half * 48);
            const float4* w4 = (const float4*)(sm + OW_OC + sub * 100 + half * 48);
            float4 a = {0.f, 0.f, 0.f, 0.f};
            #pragma unroll
            for (int i = 0; i < 12; ++i) { float4 x = x4[i], w = w4[i]; FMA4(a, w, x); }
            float part = red4(a);
            part += __shfl_xor(part, 32);
            if (lane < 27) A[A_OC + lane] = ftanh(part + b_oc);
            if (lane < 30) {
                M_reg = A[A_CO + 30 + lane];
                D_reg = A[A_CO + 60 + lane];
                A[A_COMB + 30 + lane] = M_reg;   // publish M for next step's P2
            }
        }

        // ---- P8: decision = tanh(OC @ oe_w^T + b)
        if (lane < 30) {
            const float4* x4 = (const float4*)(A + A_OC);
            const float4* w4 = (const float4*)(sm + OW_OE + lane * 28);
            float4 a = {b_oe, 0.f, 0.f, 0.f};
            #pragma unroll
            for (int i = 0; i < 7; ++i) { float4 x = x4[i], w = w4[i]; FMA4(a, w, x); }
            A[A_DEC + lane] = ftanh(red4(a));
        }

        // ---- P9: action -> global; write next obs
        if (lane < 4) {
            const float4* x4 = (const float4*)(A + A_DEC);
            const float4* w4 = (const float4*)(sm + OW_OUT + lane * 36);
            float4 a = {b_out, 0.f, 0.f, 0.f};
            #pragma unroll
            for (int i = 0; i < 8; ++i) { float4 x = x4[i], w = w4[i]; FMA4(a, w, x); }
            out[((size_t)t * NB + row) * 4 + lane] = red4(a);
        }
        if (lane < 8 && t + 1 < TS) A[A_OBS + lane] = nxt;
    }
}

extern "C" void kernel_launch(void* const* d_in, const int* in_sizes, int n_in,
                              void* d_out, int out_size, void* d_ws, size_t ws_size,
                              hipStream_t stream) {
    const float* obs        = (const float*)d_in[0];
    const float* sense_w    = (const float*)d_in[1];
    const float* sense_b    = (const float*)d_in[2];
    const float* compress_w = (const float*)d_in[3];
    const float* compress_b = (const float*)d_in[4];
    const float* expand_w   = (const float*)d_in[5];
    const float* expand_b   = (const float*)d_in[6];
    const float* gru_z_w    = (const float*)d_in[7];
    const float* gru_z_b    = (const float*)d_in[8];
    const float* gru_r_w    = (const float*)d_in[9];
    const float* gru_r_b    = (const float*)d_in[10];
    const float* gru_h_w    = (const float*)d_in[11];
    const float* gru_h_b    = (const float*)d_in[12];
    const float* ic_w       = (const float*)d_in[13];
    const float* ic_b       = (const float*)d_in[14];
    const float* iS_w       = (const float*)d_in[15];
    const float* iS_b       = (const float*)d_in[16];
    const float* iM_w       = (const float*)d_in[17];
    const float* iM_b       = (const float*)d_in[18];
    const float* iD_w       = (const float*)d_in[19];
    const float* iD_b       = (const float*)d_in[20];
    const float* phi_w      = (const float*)d_in[21];
    const float* phi_b      = (const float*)d_in[22];
    const float* oc_w       = (const float*)d_in[23];
    const float* oc_b       = (const float*)d_in[24];
    const float* oe_w       = (const float*)d_in[25];
    const float* oe_b       = (const float*)d_in[26];
    const float* out_w      = (const float*)d_in[27];
    const float* out_b      = (const float*)d_in[28];
    float* out = (float*)d_out;

    size_t shmem = (size_t)SM_TOTAL * sizeof(float);
    (void)hipFuncSetAttribute((const void*)anima_kernel,
                              hipFuncAttributeMaxDynamicSharedMemorySize, (int)shmem);
    anima_kernel<<<dim3(256), dim3(256), shmem, stream>>>(
        obs, sense_w, sense_b, compress_w, compress_b, expand_w, expand_b,
        gru_z_w, gru_z_b, gru_r_w, gru_r_b, gru_h_w, gru_h_b,
        ic_w, ic_b, iS_w, iS_b, iM_w, iM_b, iD_w, iD_b,
        phi_w, phi_b, oc_w, oc_b, oe_w, oe_b, out_w, out_b, out);
}